// Round 1
// baseline (111.873 us; speedup 1.0000x reference)
//
#include <hip/hip_runtime.h>
#include <math.h>

namespace {

constexpr int Bn = 8;
constexpr int Hn = 256;
constexpr int Wn = 256;
constexpr int HW = Hn * Wn;       // 65536
constexpr int Ntot = Bn * HW;     // 524288
constexpr float INF_F = 131138.0f; // sum(n*n for n in shape)+1 = 64+1+65536+65536+1
constexpr float EPSv = 1e-6f;

// 256-thread block sum; returns full sum to all threads. Fixed order -> deterministic.
__device__ __forceinline__ float blkred(float v, float* sm) {
    #pragma unroll
    for (int o = 32; o > 0; o >>= 1) v += __shfl_down(v, o, 64);
    int lane = threadIdx.x & 63, wid = threadIdx.x >> 6;
    __syncthreads();                // protect sm reuse across successive calls
    if (lane == 0) sm[wid] = v;
    __syncthreads();
    return sm[0] + sm[1] + sm[2] + sm[3];
}

// Kernel A: per-(h,w) pixel, loop batches. Sigmoid + dice sums + focal sum,
// mask build, and the axis-0 (batch, n=8) distance transform entirely in regs.
__global__ __launch_bounds__(256) void kA(const float* __restrict__ lg,
                                          const float* __restrict__ tg,
                                          float* __restrict__ f1,
                                          float* __restrict__ pa) {
    int t = blockIdx.x * 256 + threadIdx.x;   // 0..HW-1
    float sp = 0.f, st = 0.f, spt = 0.f, fo = 0.f;
    float fv[Bn];
    #pragma unroll
    for (int b = 0; b < Bn; b++) {
        float x  = lg[b * HW + t];
        float tv = tg[b * HW + t];
        float p  = 1.f / (1.f + expf(-x));
        sp  += p;
        st  += tv;
        spt += p * tv;
        float ce = fmaxf(x, 0.f) - x * tv + log1pf(expf(-fabsf(x)));
        float pt = p * tv + (1.f - p) * (1.f - tv);
        float om = 1.f - pt;
        fo += 0.25f * om * om * ce;          // ALPHA=0.25, GAMMA=2
        fv[b] = (tv > 0.5f) ? INF_F : 0.f;
    }
    // exact 1D squared-distance transform along batch axis (n=8)
    #pragma unroll
    for (int i = 0; i < Bn; i++) {
        float m = fv[0] + (float)(i * i);
        #pragma unroll
        for (int j = 1; j < Bn; j++) {
            int d = i - j;
            m = fminf(m, fv[j] + (float)(d * d));
        }
        f1[i * HW + t] = m;
    }
    __shared__ float sm[4];
    sp  = blkred(sp, sm);
    st  = blkred(st, sm);
    spt = blkred(spt, sm);
    fo  = blkred(fo, sm);
    if (threadIdx.x == 0) {
        float* o = pa + blockIdx.x * 4;
        o[0] = sp; o[1] = st; o[2] = spt; o[3] = fo;
    }
}

// Kernel B: DT along H. One block per (b,w) line; LDS line, broadcast reads.
__global__ __launch_bounds__(256) void kB(const float* __restrict__ f1,
                                          float* __restrict__ f2) {
    int b = blockIdx.x >> 8;       // / Wn
    int w = blockIdx.x & 255;      // % Wn
    __shared__ float ln[Hn];
    int i = threadIdx.x;
    ln[i] = f1[b * HW + i * Wn + w];
    __syncthreads();
    float m = 3.0e38f;
    #pragma unroll 8
    for (int j = 0; j < Hn; j++) {
        int d = i - j;
        m = fminf(m, ln[j] + (float)(d * d));
    }
    f2[b * HW + i * Wn + w] = m;
}

// Kernel C: DT along W (contiguous), sqrt, fused boundary term + block reduce.
__global__ __launch_bounds__(256) void kC(const float* __restrict__ f2,
                                          const float* __restrict__ lg,
                                          float* __restrict__ bp) {
    int line = blockIdx.x;         // b*Hn + h
    __shared__ float ln[Wn];
    __shared__ float sm[4];
    int i = threadIdx.x;
    ln[i] = f2[line * Wn + i];
    __syncthreads();
    float m = 3.0e38f;
    #pragma unroll 8
    for (int j = 0; j < Wn; j++) {
        int d = i - j;
        m = fminf(m, ln[j] + (float)(d * d));
    }
    float dm = sqrtf(m);
    float x  = lg[line * Wn + i];
    float p  = 1.f / (1.f + expf(-x));
    float omp = 1.f - p;
    float acc = dm * omp * omp;
    acc = blkred(acc, sm);
    if (i == 0) bp[line] = acc;
}

// Kernel D: final combine. 256 threads, one block.
__global__ __launch_bounds__(256) void kD(const float* __restrict__ pa,
                                          const float* __restrict__ bp,
                                          float* __restrict__ out) {
    __shared__ float sm[4];
    int t = threadIdx.x;
    float sp  = pa[t * 4 + 0];
    float st  = pa[t * 4 + 1];
    float spt = pa[t * 4 + 2];
    float fo  = pa[t * 4 + 3];
    float bs = 0.f;
    #pragma unroll
    for (int k = 0; k < 8; k++) bs += bp[t + k * 256];
    sp  = blkred(sp, sm);
    st  = blkred(st, sm);
    spt = blkred(spt, sm);
    fo  = blkred(fo, sm);
    bs  = blkred(bs, sm);
    if (t == 0) {
        float dice = 1.f - (2.f * spt + EPSv) / (sp + st + EPSv);
        float boundary = bs / (float)Ntot;
        float focal = fo / (float)Ntot;
        out[0] = 1.0f * dice + 0.5f * boundary + 1.0f * focal;
    }
}

} // namespace

extern "C" void kernel_launch(void* const* d_in, const int* in_sizes, int n_in,
                              void* d_out, int out_size, void* d_ws, size_t ws_size,
                              hipStream_t stream) {
    const float* lg = (const float*)d_in[0];   // logits  [8,1,256,256] f32
    const float* tg = (const float*)d_in[1];   // targets [8,1,256,256] f32
    float* ws = (float*)d_ws;
    float* f1 = ws;                      // Ntot floats (post axis-B DT)
    float* f2 = ws + Ntot;               // Ntot floats (post axis-H DT)
    float* pa = ws + 2 * Ntot;           // 256 blocks * 4 partials
    float* bp = ws + 2 * Ntot + 1024;    // 2048 boundary partials

    kA<<<HW / 256, 256, 0, stream>>>(lg, tg, f1, pa);
    kB<<<Bn * Wn, 256, 0, stream>>>(f1, f2);
    kC<<<Bn * Hn, 256, 0, stream>>>(f2, lg, bp);
    kD<<<1, 256, 0, stream>>>(pa, bp, (float*)d_out);
}

// Round 2
// 28.586 us; speedup vs baseline: 3.9135x; 3.9135x over previous
//
#include <hip/hip_runtime.h>
#include <math.h>

namespace {

constexpr int Bn = 8;
constexpr int Hn = 256;
constexpr int Wn = 256;
constexpr int HW = Hn * Wn;       // 65536
constexpr int Ntot = Bn * HW;     // 524288
constexpr float INF_F = 131138.0f; // sum(n*n for n in shape)+1
constexpr float EPSv = 1e-6f;

// 256-thread block sum; returns full sum to all threads. Fixed order -> deterministic.
__device__ __forceinline__ float blkred(float v, float* sm) {
    #pragma unroll
    for (int o = 32; o > 0; o >>= 1) v += __shfl_down(v, o, 64);
    int lane = threadIdx.x & 63, wid = threadIdx.x >> 6;
    __syncthreads();
    if (lane == 0) sm[wid] = v;
    __syncthreads();
    return sm[0] + sm[1] + sm[2] + sm[3];
}

// Kernel A: per-(h,w) pixel, loop batches. Sigmoid + dice sums + focal sum,
// mask build, and the axis-0 (batch, n=8) distance transform in regs.
// f1 written in natural [b][h][w] layout.
__global__ __launch_bounds__(256) void kA(const float* __restrict__ lg,
                                          const float* __restrict__ tg,
                                          float* __restrict__ f1,
                                          float* __restrict__ pa) {
    int t = blockIdx.x * 256 + threadIdx.x;   // 0..HW-1
    float sp = 0.f, st = 0.f, spt = 0.f, fo = 0.f;
    float fv[Bn];
    #pragma unroll
    for (int b = 0; b < Bn; b++) {
        float x  = lg[b * HW + t];
        float tv = tg[b * HW + t];
        float p  = 1.f / (1.f + expf(-x));
        sp  += p;
        st  += tv;
        spt += p * tv;
        float ce = fmaxf(x, 0.f) - x * tv + log1pf(expf(-fabsf(x)));
        float pt = p * tv + (1.f - p) * (1.f - tv);
        float om = 1.f - pt;
        fo += 0.25f * om * om * ce;          // ALPHA=0.25, GAMMA=2
        fv[b] = (tv > 0.5f) ? INF_F : 0.f;
    }
    // exact 1D squared-distance transform along batch axis (n=8)
    #pragma unroll
    for (int i = 0; i < Bn; i++) {
        float m = fv[0] + (float)(i * i);
        #pragma unroll
        for (int j = 1; j < Bn; j++) {
            int d = i - j;
            m = fminf(m, fv[j] + (float)(d * d));
        }
        f1[i * HW + t] = m;
    }
    __shared__ float sm[4];
    sp  = blkred(sp, sm);
    st  = blkred(st, sm);
    spt = blkred(spt, sm);
    fo  = blkred(fo, sm);
    if (threadIdx.x == 0) {
        float* o = pa + blockIdx.x * 4;
        o[0] = sp; o[1] = st; o[2] = spt; o[3] = fo;
    }
}

// Exact 1D DT over a 256-line staged in LDS as u[j] = f[j] + j^2:
// result(i) = i^2 + min_j (u[j] - 2*j*i). All values exact integers < 2^24
// -> bit-identical to brute force (i-j)^2 + f[j].
// 4 independent min chains (one per float4 lane) break the serial fmin dep.
__device__ __forceinline__ float dt_line(const float* u, float fi) {
    float m0 = 3.0e38f, m1 = 3.0e38f, m2 = 3.0e38f, m3 = 3.0e38f;
    const float4* u4 = reinterpret_cast<const float4*>(u);
    #pragma unroll
    for (int q = 0; q < 64; ++q) {
        float4 uu = u4[q];
        m0 = fminf(m0, fmaf((float)(-2 * (4 * q + 0)), fi, uu.x));
        m1 = fminf(m1, fmaf((float)(-2 * (4 * q + 1)), fi, uu.y));
        m2 = fminf(m2, fmaf((float)(-2 * (4 * q + 2)), fi, uu.z));
        m3 = fminf(m3, fmaf((float)(-2 * (4 * q + 3)), fi, uu.w));
    }
    return fminf(fminf(m0, m1), fminf(m2, m3)) + fi * fi;
}

// Kernel W: DT along W. One block per (b,h) line; contiguous loads/stores.
__global__ __launch_bounds__(256) void kW(const float* __restrict__ f1,
                                          float* __restrict__ g) {
    __shared__ __align__(16) float u[Wn];
    int i = threadIdx.x;
    float fi = (float)i;
    u[i] = f1[(size_t)blockIdx.x * Wn + i] + fi * fi;
    __syncthreads();
    g[(size_t)blockIdx.x * Wn + i] = dt_line(u, fi);
}

// Kernel T: per-batch 32x32 tile transpose g[b][h][w] -> gT[b][w][h].
__global__ __launch_bounds__(256) void kT(const float* __restrict__ g,
                                          float* __restrict__ gT) {
    int bid = blockIdx.x;          // b*64 + ty*8 + tx
    int b  = bid >> 6;
    int ty = (bid >> 3) & 7;
    int tx = bid & 7;
    __shared__ float t[32][33];
    int c  = threadIdx.x & 31;
    int r0 = threadIdx.x >> 5;     // 0..7
    const float* gb = g + (size_t)b * HW;
    #pragma unroll
    for (int k = 0; k < 4; ++k) {
        int r = r0 + 8 * k;
        t[r][c] = gb[(ty * 32 + r) * Wn + tx * 32 + c];
    }
    __syncthreads();
    float* gTb = gT + (size_t)b * HW;
    #pragma unroll
    for (int k = 0; k < 4; ++k) {
        int r = r0 + 8 * k;        // w within tile
        gTb[(tx * 32 + r) * Hn + ty * 32 + c] = t[c][r];
    }
}

// Kernel H: DT along H on transposed layout (contiguous lines), fused
// sqrt + boundary term + block reduction. No dm buffer round-trip.
__global__ __launch_bounds__(256) void kH(const float* __restrict__ gT,
                                          const float* __restrict__ lg,
                                          float* __restrict__ bp) {
    int b = blockIdx.x >> 8;       // line = b*Wn + w
    int w = blockIdx.x & 255;
    __shared__ __align__(16) float u[Hn];
    __shared__ float sm[4];
    int i = threadIdx.x;
    float fi = (float)i;
    u[i] = gT[(size_t)blockIdx.x * Hn + i] + fi * fi;
    __syncthreads();
    float m = dt_line(u, fi);
    float dm = sqrtf(m);
    float x = lg[(size_t)b * HW + i * Wn + w];  // one strided load/thread
    float s = 1.f / (1.f + expf(x));            // = 1 - sigmoid(x)
    float acc = dm * s * s;
    acc = blkred(acc, sm);
    if (i == 0) bp[blockIdx.x] = acc;
}

// Kernel D: final combine. 256 threads, one block.
__global__ __launch_bounds__(256) void kD(const float* __restrict__ pa,
                                          const float* __restrict__ bp,
                                          float* __restrict__ out) {
    __shared__ float sm[4];
    int t = threadIdx.x;
    float sp  = pa[t * 4 + 0];
    float st  = pa[t * 4 + 1];
    float spt = pa[t * 4 + 2];
    float fo  = pa[t * 4 + 3];
    float bs = 0.f;
    #pragma unroll
    for (int k = 0; k < 8; k++) bs += bp[t + k * 256];
    sp  = blkred(sp, sm);
    st  = blkred(st, sm);
    spt = blkred(spt, sm);
    fo  = blkred(fo, sm);
    bs  = blkred(bs, sm);
    if (t == 0) {
        float dice = 1.f - (2.f * spt + EPSv) / (sp + st + EPSv);
        float boundary = bs / (float)Ntot;
        float focal = fo / (float)Ntot;
        out[0] = 1.0f * dice + 0.5f * boundary + 1.0f * focal;
    }
}

} // namespace

extern "C" void kernel_launch(void* const* d_in, const int* in_sizes, int n_in,
                              void* d_out, int out_size, void* d_ws, size_t ws_size,
                              hipStream_t stream) {
    const float* lg = (const float*)d_in[0];   // logits  [8,1,256,256] f32
    const float* tg = (const float*)d_in[1];   // targets [8,1,256,256] f32
    float* ws = (float*)d_ws;
    float* f1 = ws;                      // Ntot floats ([b][h][w], post B-DT)
    float* g  = ws + Ntot;               // Ntot floats ([b][h][w], post W-DT)
    float* gT = ws;                      // aliases f1 (dead after kW): [b][w][h]
    float* pa = ws + 2 * Ntot;           // 256 blocks * 4 partials
    float* bp = ws + 2 * Ntot + 1024;    // 2048 boundary partials

    kA<<<HW / 256, 256, 0, stream>>>(lg, tg, f1, pa);
    kW<<<Bn * Hn, 256, 0, stream>>>(f1, g);
    kT<<<Bn * 64, 256, 0, stream>>>(g, gT);
    kH<<<Bn * Wn, 256, 0, stream>>>(gT, lg, bp);
    kD<<<1, 256, 0, stream>>>(pa, bp, (float*)d_out);
}